// Round 11
// baseline (270.156 us; speedup 1.0000x reference)
//
#include <hip/hip_runtime.h>

#define IN_SIZE 256
#define OUT_SIZE 64
#define N_NODES 512
#define FAN_IN 32
#define T_DIM 2048
#define D_DIM 832
#define TOTAL_EDGE 16384
#define BLK_F4 1088   // per-node: 1024 f4 butterfly pairs + 64 f4 entries
#define MAX_ENT 64
#define THRESH -20.0f

// DPP wave64 sum (lane 63 ends with total) — validated rounds 3..10
template <int CTRL, int RM>
__device__ __forceinline__ float dppadd(float v) {
  int m = __builtin_amdgcn_update_dpp(0, __float_as_int(v), CTRL, RM, 0xf, true);
  return v + __int_as_float(m);
}
__device__ __forceinline__ void wave_sum2(float& a, float& b) {
  a = dppadd<0x111, 0xf>(a); b = dppadd<0x111, 0xf>(b);
  a = dppadd<0x112, 0xf>(a); b = dppadd<0x112, 0xf>(b);
  a = dppadd<0x114, 0xf>(a); b = dppadd<0x114, 0xf>(b);
  a = dppadd<0x118, 0xf>(a); b = dppadd<0x118, 0xf>(b);
  a = dppadd<0x142, 0xa>(a); b = dppadd<0x142, 0xa>(b);
  a = dppadd<0x143, 0xc>(a); b = dppadd<0x143, 0xc>(b);
}
__device__ __forceinline__ float rl63(float v) {
  return __int_as_float(__builtin_amdgcn_readlane(__float_as_int(v), 63));
}

// ---------------------------------------------------------------------------
// KV build (t-major, rows staged in LDS) — r8's validated 512-block/4-row
// version. Writes (k,v) t-order into blk KV area; slot 2047 = 0.
// ---------------------------------------------------------------------------
__global__ __launch_bounds__(256) void kv_kernel(
    const float* __restrict__ actives, const int* __restrict__ in_idxs,
    const float* __restrict__ weights, float2* __restrict__ KVd) {
  __shared__ float rows[4][833];
  __shared__ int s_idx[64 * FAN_IN];
  __shared__ float2 s_w[64 * FAN_IN];
  int tid = threadIdx.x;
  int tb = blockIdx.x * 4;
  for (int i = tid; i < 4 * D_DIM; i += 256) {
    int r = i / D_DIM, c = i - r * D_DIM;
    int t = tb + r;
    rows[r][c] = (t < T_DIM - 1) ? actives[(size_t)(t + 1) * D_DIM + c] : 0.f;
  }
  int tl = tid & 3, ng = tid >> 2;  // 4 t x 64 nodes
  for (int tile = 0; tile < 8; ++tile) {
    __syncthreads();
    int n0 = tile * 64;
    for (int i = tid; i < 64 * FAN_IN; i += 256) {
      int g = n0 * FAN_IN + i;
      s_idx[i] = in_idxs[g];
      const float* wp = weights + (size_t)g * 3;
      s_w[i] = make_float2(wp[1], wp[2]);
    }
    __syncthreads();
    const int* ip = &s_idx[ng * FAN_IN];
    const float2* wp = &s_w[ng * FAN_IN];
    float k = 0.f, v = 0.f;
#pragma unroll 8
    for (int f = 0; f < FAN_IN; ++f) {
      float a = rows[tl][ip[f]];
      float2 w = wp[f];
      k = fmaf(w.x, a, k);
      v = fmaf(w.y, a, v);
    }
    KVd[(size_t)(n0 + ng) * (2 * BLK_F4) + tb + tl] = make_float2(k, v);
  }
}

// ---------------------------------------------------------------------------
// Block build — r10's validated version. Butterfly pairs + entries (c>node) +
// meta + base dot.
// ---------------------------------------------------------------------------
__global__ __launch_bounds__(256) void block_kernel(
    const float* __restrict__ x, const int* __restrict__ in_idxs,
    const float* __restrict__ weights, float4* __restrict__ blk,
    float4* __restrict__ meta_g, float4* __restrict__ Qb) {
  __shared__ float2 skv[T_DIM], sbk[T_DIM];
  __shared__ int hist[64];
  __shared__ float smx[4], smn[4];
  __shared__ float4 sEnt[MAX_ENT];
  __shared__ int ecnt;
  int node = blockIdx.x, tid = threadIdx.x;
  if (tid == 0) ecnt = 0;
  const float2* src = (const float2*)(blk + (size_t)node * BLK_F4);
  float mx = -3.4e38f, mn = 3.4e38f;
#pragma unroll
  for (int j = 0; j < 8; ++j) {
    int t = j * 256 + tid;
    float2 kv = (t < 2047) ? src[t] : make_float2(0.f, 0.f);
    skv[t] = kv;
    if (t < 2047) { mx = fmaxf(mx, kv.x); mn = fminf(mn, kv.x); }
  }
  if (tid < 64) hist[tid] = 0;
#pragma unroll
  for (int off = 32; off > 0; off >>= 1) {
    mx = fmaxf(mx, __shfl_xor(mx, off));
    mn = fminf(mn, __shfl_xor(mn, off));
  }
  if ((tid & 63) == 0) { smx[tid >> 6] = mx; smn[tid >> 6] = mn; }
  __syncthreads();
  float kmax = fmaxf(fmaxf(smx[0], smx[1]), fmaxf(smx[2], smx[3]));
  float kmin = fminf(fminf(smn[0], smn[1]), fminf(smn[2], smn[3]));
  float invbw = 64.0f / (kmax - kmin);
#pragma unroll
  for (int j = 0; j < 8; ++j) {
    int t = j * 256 + tid;
    if (t < 2047) {
      int b = (int)((skv[t].x - kmin) * invbw);
      b = b < 0 ? 0 : (b > 63 ? 63 : b);
      atomicAdd(&hist[b], 1);
    }
  }
  {
    int target = IN_SIZE + node;
    for (int e = tid; e < TOTAL_EDGE; e += 256) {
      if (in_idxs[e] == target) {
        int c = e >> 5;
        if (c > node) {
          int p = atomicAdd(&ecnt, 1);
          if (p < MAX_ENT) {
            const float* wp = weights + (size_t)e * 3;
            sEnt[p] = make_float4(__int_as_float(c), wp[0], wp[1], wp[2]);
          }
        }
      }
    }
  }
  __syncthreads();
  if (tid < 64) {
    int v = hist[tid];
    int incl = v;
#pragma unroll
    for (int d = 1; d < 64; d <<= 1) {
      int u = __shfl_up(incl, d);
      if (tid >= d) incl += u;
    }
    hist[tid] = incl - v;
  }
  if (tid == 0) sbk[2047] = make_float2(0.f, 0.f);
  __syncthreads();
#pragma unroll
  for (int j = 0; j < 8; ++j) {
    int t = j * 256 + tid;
    if (t < 2047) {
      int b = (int)((skv[t].x - kmin) * invbw);
      b = b < 0 ? 0 : (b > 63 ? 63 : b);
      int p = atomicAdd(&hist[b], 1);
      sbk[p] = skv[t];
    }
  }
  if (tid < 32) {
    int g = node * FAN_IN + tid;
    int idx = in_idxs[g];
    const float* wp = weights + (size_t)g * 3;
    float a = (idx < IN_SIZE) ? x[idx] : 0.f;
    float p0 = a * wp[0], p1 = a * wp[1], p2 = a * wp[2];
#pragma unroll
    for (int off = 16; off > 0; off >>= 1) {
      p0 += __shfl_xor(p0, off);
      p1 += __shfl_xor(p1, off);
      p2 += __shfl_xor(p2, off);
    }
    if (tid == 0) Qb[node] = make_float4(p0, p1, p2, 0.f);
  }
  __syncthreads();
  float4* B = blk + (size_t)node * BLK_F4;
  for (int i = tid; i < 1024; i += 256) {
    float2 a = sbk[i];
    float2 d = sbk[2046 - i];
    B[i] = make_float4(a.x, a.y, d.x, d.y);
  }
  int cnt = ecnt < MAX_ENT ? ecnt : MAX_ENT;
  if (tid < MAX_ENT)
    B[1024 + tid] = (tid < cnt) ? sEnt[tid] : make_float4(0.f, 0.f, 0.f, 0.f);
  if (tid == 0)
    meta_g[3 * node + 0] =
        make_float4(kmax, kmin, __int_as_float(cnt), sbk[64].x);
  if (tid == 1)
    meta_g[3 * node + 1] =
        make_float4(sbk[1982].x, sbk[256].x, sbk[1790].x, sbk[512].x);
  if (tid == 2)
    meta_g[3 * node + 2] = make_float4(sbk[1534].x, 0.f, 0.f, 0.f);
}

// ---------------------------------------------------------------------------
// Level sweep v2: 1 block x 1024 thr (16 waves).
//  - exact levels via single-wave chunk-sequential shfl propagation (~6 us,
//    replaces ~40 us 16-wave Bellman-Ford)
//  - main loop: next-level chunk0+ent+t1 prefetch issued at TOP of level
//    body (static addresses) so latency hides behind current level compute;
//    t1 register-resident kills the 30% p1 stall; t2/t3 on-demand.
// ---------------------------------------------------------------------------
__global__ __launch_bounds__(1024) void sweep_kernel(
    const int* __restrict__ in_idxs, const float4* __restrict__ Qb,
    const float4* __restrict__ meta_g, const float4* __restrict__ blk,
    float* __restrict__ out) {
  __shared__ float4 sQKV[N_NODES];
  __shared__ float4 sMeta[N_NODES][3];
  __shared__ int sLevel[N_NODES];
  __shared__ int sOrder[N_NODES];
  __shared__ int sStart[N_NODES + 2];
  __shared__ int sCur[N_NODES];
  __shared__ int wtot[8];
  __shared__ int sNlev;
  __shared__ float souts[OUT_SIZE];
  const int tid = threadIdx.x;
  const int lane = tid & 63;
  const int w = tid >> 6;

  for (int n = tid; n < N_NODES; n += 1024) {
    sQKV[n] = Qb[n];
    sMeta[n][0] = meta_g[3 * n + 0];
    sMeta[n][1] = meta_g[3 * n + 1];
    sMeta[n][2] = meta_g[3 * n + 2];
  }
  if (tid == 0) sNlev = 1;
  __syncthreads();

  // ---- exact levels: wave 0, 8 sequential chunks of 64, shfl propagation
  if (w == 0) {
    int pr[32];
    {
      const int4* ip = (const int4*)(in_idxs + lane * FAN_IN);
#pragma unroll
      for (int j = 0; j < 8; ++j) {
        int4 v = ip[j];
        pr[4 * j + 0] = v.x; pr[4 * j + 1] = v.y;
        pr[4 * j + 2] = v.z; pr[4 * j + 3] = v.w;
      }
    }
    for (int c = 0; c < 8; ++c) {
      int cbase = c * 64;
      int nodeN = cbase + lane;
      int prn[32];
      if (c < 7) {  // prefetch next chunk's pred list
        const int4* ip = (const int4*)(in_idxs + (nodeN + 64) * FAN_IN);
#pragma unroll
        for (int j = 0; j < 8; ++j) {
          int4 v = ip[j];
          prn[4 * j + 0] = v.x; prn[4 * j + 1] = v.y;
          prn[4 * j + 2] = v.z; prn[4 * j + 3] = v.w;
        }
      }
      int baseLvl = 0;
#pragma unroll
      for (int f = 0; f < 32; ++f) {
        int pf = pr[f] - IN_SIZE;
        if (pf >= 0 && pf < nodeN && pf < cbase) {
          int lp = sLevel[pf] + 1;  // earlier chunk: final (same-wave order)
          baseLvl = baseLvl > lp ? baseLvl : lp;
        }
      }
      int lvl = baseLvl;
      for (int it = 0; it < 64; ++it) {
        int nl = baseLvl;
#pragma unroll
        for (int f = 0; f < 32; ++f) {
          int pf = pr[f] - IN_SIZE;
          bool inch = (pf >= cbase) && (pf < nodeN);
          int v = __shfl(lvl, (pf - cbase) & 63) + 1;
          if (inch && v > nl) nl = v;
        }
        bool ch = (nl != lvl);
        lvl = nl;
        if (!__any(ch)) break;
      }
      sLevel[nodeN] = lvl;
#pragma unroll
      for (int f = 0; f < 32; ++f) pr[f] = prn[f];
    }
  }
  __syncthreads();

  // ---- counting sort by level
  for (int i = tid; i < N_NODES; i += 1024) sCur[i] = 0;
  __syncthreads();
  if (tid < N_NODES) {
    atomicAdd(&sCur[sLevel[tid]], 1);
    atomicMax(&sNlev, sLevel[tid] + 1);
  }
  __syncthreads();
  int incl = 0;
  if (tid < N_NODES) {
    incl = sCur[tid];
#pragma unroll
    for (int d = 1; d < 64; d <<= 1) {
      int u = __shfl_up(incl, d);
      if ((tid & 63) >= d) incl += u;
    }
    if ((tid & 63) == 63) wtot[tid >> 6] = incl;
  }
  __syncthreads();
  if (tid < N_NODES) {
    int add = 0;
    for (int ww = 0; ww < (tid >> 6); ++ww) add += wtot[ww];
    sStart[tid + 1] = incl + add;
    if (tid == 0) { sStart[0] = 0; sStart[N_NODES + 1] = N_NODES; }
  }
  __syncthreads();
  for (int i = tid; i < N_NODES; i += 1024) sCur[i] = sStart[i];
  __syncthreads();
  if (tid < N_NODES) {
    int p = atomicAdd(&sCur[sLevel[tid]], 1);
    sOrder[p] = tid;
  }
  __syncthreads();
  const int nlev = sNlev;

  auto process = [&](int node, float4 C0, float4 ENT, float4* T1) {
    float4 qv = sQKV[node];
    float4 m0 = sMeta[node][0], m1 = sMeta[node][1], m2 = sMeta[node][2];
    float q = qv.x, kl = qv.y, vl = qv.z;
    int cnt = __float_as_int(m0.z);
    float m = fmaxf(fmaxf(q * m0.x, q * m0.y), q * kl);
    bool p1 = fmaxf(q * m0.w, q * m1.x) - m >= THRESH;   // pairs 64..255
    bool p2 = p1 && (fmaxf(q * m1.y, q * m1.z) - m >= THRESH);  // 256..511
    bool p3 = p2 && (fmaxf(q * m1.w, q * m2.x) - m >= THRESH);  // 512..1023
    const float4* B = blk + (size_t)node * BLK_F4;
    float4 t2[4], t3[8];
    if (p2) {
#pragma unroll
      for (int t = 0; t < 4; ++t) t2[t] = B[256 + 64 * t + lane];
    }
    if (p3) {
#pragma unroll
      for (int t = 0; t < 8; ++t) t3[t] = B[512 + 64 * t + lane];
    }
    float el = __expf(q * kl - m);
    float w0 = __expf(fmaf(q, C0.x, -m));
    float w1 = __expf(fmaf(q, C0.z, -m));
    float sw = w0 + w1;
    float swv = fmaf(w0, C0.y, w1 * C0.w);
    if (p1) {
#pragma unroll
      for (int t = 0; t < 3; ++t) {
        float a0 = __expf(fmaf(q, T1[t].x, -m));
        float a1 = __expf(fmaf(q, T1[t].z, -m));
        sw += a0 + a1;
        swv = fmaf(a0, T1[t].y, fmaf(a1, T1[t].w, swv));
      }
    }
    if (p2) {
#pragma unroll
      for (int t = 0; t < 4; ++t) {
        float a0 = __expf(fmaf(q, t2[t].x, -m));
        float a1 = __expf(fmaf(q, t2[t].z, -m));
        sw += a0 + a1;
        swv = fmaf(a0, t2[t].y, fmaf(a1, t2[t].w, swv));
      }
    }
    if (p3) {
#pragma unroll
      for (int t = 0; t < 8; ++t) {
        float a0 = __expf(fmaf(q, t3[t].x, -m));
        float a1 = __expf(fmaf(q, t3[t].z, -m));
        if (t == 7 && lane == 63) a1 = 0.f;  // pair 1023 desc = median dup
        sw += a0 + a1;
        swv = fmaf(a0, t3[t].y, fmaf(a1, t3[t].w, swv));
      }
    }
    wave_sum2(sw, swv);
    float S = rl63(sw) + el;
    float SV = fmaf(el, vl, rl63(swv));
    float z = SV * __builtin_amdgcn_rcpf(S);
    float eo = __expf(2.f * z);
    float o = 1.f - 2.f * __builtin_amdgcn_rcpf(eo + 1.f);
    if (lane == 0 && node >= N_NODES - OUT_SIZE)
      souts[node - (N_NODES - OUT_SIZE)] = o;
    if (lane < cnt) {
      int n = __float_as_int(ENT.x);
      atomicAdd(&sQKV[n].x, o * ENT.y);
      atomicAdd(&sQKV[n].y, o * ENT.z);
      atomicAdd(&sQKV[n].z, o * ENT.w);
    }
  };

  // preload level 0 assignment (sOrder valid after sort barrier)
  int pn = -1;
  float4 c0, ent, t1[3];
  {
    int j = sStart[0] + w;
    if (j < sStart[1]) {
      pn = sOrder[j];
      const float4* B = blk + (size_t)pn * BLK_F4;
      c0 = B[lane];
      ent = B[1024 + lane];
#pragma unroll
      for (int t = 0; t < 3; ++t) t1[t] = B[64 + 64 * t + lane];
    }
  }

  for (int L = 0; L < nlev; ++L) {
    // 1. issue next-level prefetch FIRST (static addrs; hides behind compute)
    int nn = -1;
    float4 c0n, entn, t1n[3];
    if (L + 1 < nlev) {
      int j = sStart[L + 1] + w;
      if (j < sStart[L + 2]) {
        nn = sOrder[j];
        const float4* B = blk + (size_t)nn * BLK_F4;
        c0n = B[lane];
        entn = B[1024 + lane];
#pragma unroll
        for (int t = 0; t < 3; ++t) t1n[t] = B[64 + 64 * t + lane];
      }
    }
    // 2. process current level
    if (pn >= 0) process(pn, c0, ent, t1);
    // 3. overflow nodes (level wider than 16 waves): fully on-demand (rare)
    for (int i = sStart[L] + w + 16; i < sStart[L + 1]; i += 16) {
      int n2 = sOrder[i];
      const float4* B = blk + (size_t)n2 * BLK_F4;
      float4 ot1[3];
#pragma unroll
      for (int t = 0; t < 3; ++t) ot1[t] = B[64 + 64 * t + lane];
      process(n2, B[lane], B[1024 + lane], ot1);
    }
    __syncthreads();  // level L scatters visible for level L+1 reads
    pn = nn;
    c0 = c0n;
    ent = entn;
#pragma unroll
    for (int t = 0; t < 3; ++t) t1[t] = t1n[t];
  }
  if (tid < OUT_SIZE) out[tid] = souts[tid];
}

// ---------------------------------------------------------------------------
extern "C" void kernel_launch(void* const* d_in, const int* in_sizes, int n_in,
                              void* d_out, int out_size, void* d_ws,
                              size_t ws_size, hipStream_t stream) {
  const float* x = (const float*)d_in[0];
  const float* actives = (const float*)d_in[1];
  const float* weights = (const float*)d_in[2];
  const int* in_idxs = (const int*)d_in[3];
  float* out = (float*)d_out;

  // workspace (~9.0 MB): blk | meta_g | Qb
  char* ws = (char*)d_ws;
  float4* blk = (float4*)ws;  // 512 * 1088 * 16 = 8,912,896 B
  size_t off = (size_t)N_NODES * BLK_F4 * 16;
  float4* meta_g = (float4*)(ws + off); off += (size_t)N_NODES * 3 * 16;
  float4* Qb = (float4*)(ws + off);

  kv_kernel<<<T_DIM / 4, 256, 0, stream>>>(actives, in_idxs, weights,
                                           (float2*)blk);
  block_kernel<<<N_NODES, 256, 0, stream>>>(x, in_idxs, weights, blk, meta_g,
                                            Qb);
  sweep_kernel<<<1, 1024, 0, stream>>>(in_idxs, Qb, meta_g, blk, out);
}